// Round 5
// baseline (44.476 us; speedup 1.0000x reference)
//
#include <hip/hip_runtime.h>

#define TPB 256   // 2 matrices per thread, packed into v2f lanes

typedef float v2f __attribute__((ext_vector_type(2)));
typedef int   v2i __attribute__((ext_vector_type(2)));

static __device__ __forceinline__ v2f sqrt2(v2f a){
    v2f r; r.x = __builtin_amdgcn_sqrtf(a.x); r.y = __builtin_amdgcn_sqrtf(a.y); return r;
}
static __device__ __forceinline__ v2f rsq2(v2f a){
    v2f r; r.x = __builtin_amdgcn_rsqf(a.x); r.y = __builtin_amdgcn_rsqf(a.y); return r;
}
static __device__ __forceinline__ v2f csign2(v2f x, v2f y){
    v2f r; r.x = copysignf(x.x, y.x); r.y = copysignf(x.y, y.y); return r;
}
static __device__ __forceinline__ v2f fabs2(v2f x){
    v2f r; r.x = fabsf(x.x); r.y = fabsf(x.y); return r;
}
static __device__ __forceinline__ v2f sel2(v2i m, v2f a, v2f b){
    v2f r; r.x = m.x ? a.x : b.x; r.y = m.y ? a.y : b.y; return r;
}
static __device__ __forceinline__ void rot2(v2f &p, v2f &q, v2f c, v2f s){
    v2f x = p, y = q; p = c*x - s*y; q = s*x + c*y;
}
static __device__ __forceinline__ void rotg2(v2f &p, v2f &q, v2f c, v2f s){
    v2f x = p, y = q; p = c*x + s*y; q = c*y - s*x;
}

// Exact cyclic-Jacobi rotation (2 transcendentals), branchless.
static __device__ __forceinline__ void jrot2(v2f &app, v2f &aqq, v2f &apq,
                                             v2f &arp, v2f &arq,
                                             v2f &v0p, v2f &v1p, v2f &v2p,
                                             v2f &v0q, v2f &v1q, v2f &v2q)
{
    v2f d   = aqq - app;
    v2f w   = apq + apq;
    v2f nrm = d*d + w*w;
    v2f rr  = sqrt2(nrm);
    v2f sr  = csign2(rr, d);
    v2f den = d + sr;
    v2f inv = rsq2(den*den + w*w);
    v2f c   = fabs2(den) * inv;
    v2f s   = w * csign2(inv, den);
    v2i tiny = nrm < (v2f)1e-30f;
    c = sel2(tiny, (v2f)1.0f, c);
    s = sel2(tiny, (v2f)0.0f, s);
    v2f sum = app + aqq;
    v2f lo  = 0.5f*(sum - sr);
    app = lo; aqq = sum - lo; apq = (v2f)0.0f;
    rot2(arp, arq, c, s);
    rot2(v0p, v0q, c, s);
    rot2(v1p, v1q, c, s);
    rot2(v2p, v2q, c, s);
}

static __device__ __forceinline__ void givens2(v2f a1, v2f a2,
    v2f &bi0, v2f &bi1, v2f &bi2, v2f &bj0, v2f &bj1, v2f &bj2,
    v2f &ui0, v2f &ui1, v2f &ui2, v2f &uj0, v2f &uj1, v2f &uj2)
{
    v2f d  = a1*a1 + a2*a2;
    v2f rr = rsq2(d);
    v2i ok = d > (v2f)1e-30f;
    v2f c  = sel2(ok, a1*rr, (v2f)1.0f);
    v2f s  = sel2(ok, a2*rr, (v2f)0.0f);
    rotg2(bi0, bj0, c, s);
    rotg2(bi1, bj1, c, s);
    rotg2(bi2, bj2, c, s);
    rotg2(ui0, uj0, c, s);
    rotg2(ui1, uj1, c, s);
    rotg2(ui2, uj2, c, s);
}

static __device__ __forceinline__ void solve2(
    v2f m00, v2f m01, v2f m02,
    v2f m10, v2f m11, v2f m12,
    v2f m20, v2f m21, v2f m22,
    v2f &r00, v2f &r01, v2f &r02,
    v2f &r10, v2f &r11, v2f &r12,
    v2f &r20, v2f &r21, v2f &r22)
{
    v2f a00 = m00*m00 + m10*m10 + m20*m20;
    v2f a11 = m01*m01 + m11*m11 + m21*m21;
    v2f a22 = m02*m02 + m12*m12 + m22*m22;
    v2f a01 = m00*m01 + m10*m11 + m20*m21;
    v2f a02 = m00*m02 + m10*m12 + m20*m22;
    v2f a12 = m01*m02 + m11*m12 + m21*m22;

    v2f v00 = (v2f)1.0f, v01 = (v2f)0.0f, v02 = (v2f)0.0f;
    v2f v10 = (v2f)0.0f, v11 = (v2f)1.0f, v12 = (v2f)0.0f;
    v2f v20 = (v2f)0.0f, v21 = (v2f)0.0f, v22 = (v2f)1.0f;

    #pragma unroll
    for (int sw = 0; sw < 4; ++sw) {
        jrot2(a00, a11, a01, a02, a12, v00, v10, v20, v01, v11, v21);
        jrot2(a00, a22, a02, a01, a12, v00, v10, v20, v02, v12, v22);
        jrot2(a11, a22, a12, a01, a02, v01, v11, v21, v02, v12, v22);
    }

    v2f t;
    {
        v2i c01 = a00 < a11;
        t = a00; a00 = sel2(c01, a11, a00); a11 = sel2(c01, t, a11);
        t = v00; v00 = sel2(c01, v01, v00); v01 = sel2(c01, -t, v01);
        t = v10; v10 = sel2(c01, v11, v10); v11 = sel2(c01, -t, v11);
        t = v20; v20 = sel2(c01, v21, v20); v21 = sel2(c01, -t, v21);
    }
    {
        v2i c02 = a00 < a22;
        t = a00; a00 = sel2(c02, a22, a00); a22 = sel2(c02, t, a22);
        t = v00; v00 = sel2(c02, v02, v00); v02 = sel2(c02, -t, v02);
        t = v10; v10 = sel2(c02, v12, v10); v12 = sel2(c02, -t, v12);
        t = v20; v20 = sel2(c02, v22, v20); v22 = sel2(c02, -t, v22);
    }
    {
        v2i c12 = a11 < a22;
        t = a11; a11 = sel2(c12, a22, a11); a22 = sel2(c12, t, a22);
        t = v01; v01 = sel2(c12, v02, v01); v02 = sel2(c12, -t, v02);
        t = v11; v11 = sel2(c12, v12, v11); v12 = sel2(c12, -t, v12);
        t = v21; v21 = sel2(c12, v22, v21); v22 = sel2(c12, -t, v22);
    }

    v2f b00 = m00*v00 + m01*v10 + m02*v20;
    v2f b01 = m00*v01 + m01*v11 + m02*v21;
    v2f b02 = m00*v02 + m01*v12 + m02*v22;
    v2f b10 = m10*v00 + m11*v10 + m12*v20;
    v2f b11 = m10*v01 + m11*v11 + m12*v21;
    v2f b12 = m10*v02 + m11*v12 + m12*v22;
    v2f b20 = m20*v00 + m21*v10 + m22*v20;
    v2f b21 = m20*v01 + m21*v11 + m22*v21;
    v2f b22 = m20*v02 + m21*v12 + m22*v22;

    v2f u00 = (v2f)1.0f, u01 = (v2f)0.0f, u02 = (v2f)0.0f;
    v2f u10 = (v2f)0.0f, u11 = (v2f)1.0f, u12 = (v2f)0.0f;
    v2f u20 = (v2f)0.0f, u21 = (v2f)0.0f, u22 = (v2f)1.0f;

    givens2(b00, b10, b00, b01, b02, b10, b11, b12,
            u00, u10, u20, u01, u11, u21);
    givens2(b00, b20, b00, b01, b02, b20, b21, b22,
            u00, u10, u20, u02, u12, u22);
    givens2(b11, b21, b10, b11, b12, b20, b21, b22,
            u01, u11, u21, u02, u12, u22);

    r00 = u00*v00 + u01*v01 + u02*v02;
    r01 = u00*v10 + u01*v11 + u02*v12;
    r02 = u00*v20 + u01*v21 + u02*v22;
    r10 = u10*v00 + u11*v01 + u12*v02;
    r11 = u10*v10 + u11*v11 + u12*v12;
    r12 = u10*v20 + u11*v21 + u12*v22;
    r20 = u20*v00 + u21*v01 + u22*v02;
    r21 = u20*v10 + u21*v11 + u22*v12;
    r22 = u20*v20 + u21*v21 + u22*v22;
}

// No LDS, no barriers: each thread owns 2 ADJACENT matrices = 18 contiguous
// floats = 72 B (8B-aligned) -> nine float2 loads / stores straight to
// registers. A wave's loads densely cover 4.6 KB, so every cache line is
// fully consumed (no over-fetch). Latency hiding comes from occupancy
// (no LDS -> up to ~24+ waves/CU) instead of block-wide barriers.
__global__ __launch_bounds__(TPB) void svdo_kernel(const float* __restrict__ x,
                                                   float* __restrict__ out,
                                                   int nmat)
{
    const int g = blockIdx.x * TPB + threadIdx.x;
    const int m2 = g * 2;
    if (m2 >= nmat) return;
    const size_t base = (size_t)m2 * 9;
    const bool full = (m2 + 2 <= nmat);

    float x0,x1,x2,x3,x4,x5,x6,x7,x8,x9,x10,x11,x12,x13,x14,x15,x16,x17;
    if (full) {
        const float2* p = (const float2*)(x + base);   // 8B-aligned (72*g bytes)
        float2 q0=p[0], q1=p[1], q2=p[2], q3=p[3], q4=p[4], q5=p[5], q6=p[6], q7=p[7], q8=p[8];
        x0 =q0.x; x1 =q0.y; x2 =q1.x; x3 =q1.y; x4 =q2.x; x5 =q2.y;
        x6 =q3.x; x7 =q3.y; x8 =q4.x; x9 =q4.y; x10=q5.x; x11=q5.y;
        x12=q6.x; x13=q6.y; x14=q7.x; x15=q7.y; x16=q8.x; x17=q8.y;
    } else {
        // odd tail: single matrix, duplicate into lane .y
        x0=x[base+0]; x1=x[base+1]; x2=x[base+2];
        x3=x[base+3]; x4=x[base+4]; x5=x[base+5];
        x6=x[base+6]; x7=x[base+7]; x8=x[base+8];
        x9=x0; x10=x1; x11=x2; x12=x3; x13=x4; x14=x5; x15=x6; x16=x7; x17=x8;
    }

    v2f r00, r01, r02, r10, r11, r12, r20, r21, r22;
    solve2((v2f){x0,x9 }, (v2f){x1,x10}, (v2f){x2,x11},
           (v2f){x3,x12}, (v2f){x4,x13}, (v2f){x5,x14},
           (v2f){x6,x15}, (v2f){x7,x16}, (v2f){x8,x17},
           r00, r01, r02, r10, r11, r12, r20, r21, r22);

    if (full) {
        float2* o = (float2*)(out + base);
        o[0] = make_float2(r00.x, r01.x);
        o[1] = make_float2(r02.x, r10.x);
        o[2] = make_float2(r11.x, r12.x);
        o[3] = make_float2(r20.x, r21.x);
        o[4] = make_float2(r22.x, r00.y);
        o[5] = make_float2(r01.y, r02.y);
        o[6] = make_float2(r10.y, r11.y);
        o[7] = make_float2(r12.y, r20.y);
        o[8] = make_float2(r21.y, r22.y);
    } else {
        out[base+0]=r00.x; out[base+1]=r01.x; out[base+2]=r02.x;
        out[base+3]=r10.x; out[base+4]=r11.x; out[base+5]=r12.x;
        out[base+6]=r20.x; out[base+7]=r21.x; out[base+8]=r22.x;
    }
}

extern "C" void kernel_launch(void* const* d_in, const int* in_sizes, int n_in,
                              void* d_out, int out_size, void* d_ws, size_t ws_size,
                              hipStream_t stream)
{
    (void)n_in; (void)d_ws; (void)ws_size; (void)out_size;
    const float* x = (const float*)d_in[0];
    float* out = (float*)d_out;
    const int nmat = in_sizes[0] / 9;
    const int mats_per_block = TPB * 2;
    const int grid = (nmat + mats_per_block - 1) / mats_per_block;
    svdo_kernel<<<grid, TPB, 0, stream>>>(x, out, nmat);
}

// Round 6
// 39.966 us; speedup vs baseline: 1.1128x; 1.1128x over previous
//
#include <hip/hip_runtime.h>

#define TPB 256
#define MPW 128               // matrices per wave
#define FPW (MPW * 9)         // 1152 floats = 4608 B per wave region
#define F4PW (FPW / 4)        // 288 float4 per wave region
#define MPB (MPW * 4)         // 512 matrices per block (4 waves)

typedef float v2f __attribute__((ext_vector_type(2)));
typedef int   v2i __attribute__((ext_vector_type(2)));

static __device__ __forceinline__ v2f sqrt2(v2f a){
    v2f r; r.x = __builtin_amdgcn_sqrtf(a.x); r.y = __builtin_amdgcn_sqrtf(a.y); return r;
}
static __device__ __forceinline__ v2f rsq2(v2f a){
    v2f r; r.x = __builtin_amdgcn_rsqf(a.x); r.y = __builtin_amdgcn_rsqf(a.y); return r;
}
static __device__ __forceinline__ v2f csign2(v2f x, v2f y){
    v2f r; r.x = copysignf(x.x, y.x); r.y = copysignf(x.y, y.y); return r;
}
static __device__ __forceinline__ v2f fabs2(v2f x){
    v2f r; r.x = fabsf(x.x); r.y = fabsf(x.y); return r;
}
static __device__ __forceinline__ v2f sel2(v2i m, v2f a, v2f b){
    v2f r; r.x = m.x ? a.x : b.x; r.y = m.y ? a.y : b.y; return r;
}
static __device__ __forceinline__ void rot2(v2f &p, v2f &q, v2f c, v2f s){
    v2f x = p, y = q; p = c*x - s*y; q = s*x + c*y;
}
static __device__ __forceinline__ void rotg2(v2f &p, v2f &q, v2f c, v2f s){
    v2f x = p, y = q; p = c*x + s*y; q = c*y - s*x;
}

// Exact cyclic-Jacobi rotation (2 transcendentals), branchless. (unchanged)
static __device__ __forceinline__ void jrot2(v2f &app, v2f &aqq, v2f &apq,
                                             v2f &arp, v2f &arq,
                                             v2f &v0p, v2f &v1p, v2f &v2p,
                                             v2f &v0q, v2f &v1q, v2f &v2q)
{
    v2f d   = aqq - app;
    v2f w   = apq + apq;
    v2f nrm = d*d + w*w;
    v2f rr  = sqrt2(nrm);
    v2f sr  = csign2(rr, d);
    v2f den = d + sr;
    v2f inv = rsq2(den*den + w*w);
    v2f c   = fabs2(den) * inv;
    v2f s   = w * csign2(inv, den);
    v2i tiny = nrm < (v2f)1e-30f;
    c = sel2(tiny, (v2f)1.0f, c);
    s = sel2(tiny, (v2f)0.0f, s);
    v2f sum = app + aqq;
    v2f lo  = 0.5f*(sum - sr);
    app = lo; aqq = sum - lo; apq = (v2f)0.0f;
    rot2(arp, arq, c, s);
    rot2(v0p, v0q, c, s);
    rot2(v1p, v1q, c, s);
    rot2(v2p, v2q, c, s);
}

static __device__ __forceinline__ void givens2(v2f a1, v2f a2,
    v2f &bi0, v2f &bi1, v2f &bi2, v2f &bj0, v2f &bj1, v2f &bj2,
    v2f &ui0, v2f &ui1, v2f &ui2, v2f &uj0, v2f &uj1, v2f &uj2)
{
    v2f d  = a1*a1 + a2*a2;
    v2f rr = rsq2(d);
    v2i ok = d > (v2f)1e-30f;
    v2f c  = sel2(ok, a1*rr, (v2f)1.0f);
    v2f s  = sel2(ok, a2*rr, (v2f)0.0f);
    rotg2(bi0, bj0, c, s);
    rotg2(bi1, bj1, c, s);
    rotg2(bi2, bj2, c, s);
    rotg2(ui0, uj0, c, s);
    rotg2(ui1, uj1, c, s);
    rotg2(ui2, uj2, c, s);
}

// Full SO(3) projection for 2 packed matrices (unchanged from rounds 2-5).
static __device__ __forceinline__ void solve2(
    v2f m00, v2f m01, v2f m02,
    v2f m10, v2f m11, v2f m12,
    v2f m20, v2f m21, v2f m22,
    v2f &r00, v2f &r01, v2f &r02,
    v2f &r10, v2f &r11, v2f &r12,
    v2f &r20, v2f &r21, v2f &r22)
{
    v2f a00 = m00*m00 + m10*m10 + m20*m20;
    v2f a11 = m01*m01 + m11*m11 + m21*m21;
    v2f a22 = m02*m02 + m12*m12 + m22*m22;
    v2f a01 = m00*m01 + m10*m11 + m20*m21;
    v2f a02 = m00*m02 + m10*m12 + m20*m22;
    v2f a12 = m01*m02 + m11*m12 + m21*m22;

    v2f v00 = (v2f)1.0f, v01 = (v2f)0.0f, v02 = (v2f)0.0f;
    v2f v10 = (v2f)0.0f, v11 = (v2f)1.0f, v12 = (v2f)0.0f;
    v2f v20 = (v2f)0.0f, v21 = (v2f)0.0f, v22 = (v2f)1.0f;

    #pragma unroll
    for (int sw = 0; sw < 4; ++sw) {
        jrot2(a00, a11, a01, a02, a12, v00, v10, v20, v01, v11, v21);
        jrot2(a00, a22, a02, a01, a12, v00, v10, v20, v02, v12, v22);
        jrot2(a11, a22, a12, a01, a02, v01, v11, v21, v02, v12, v22);
    }

    v2f t;
    {
        v2i c01 = a00 < a11;
        t = a00; a00 = sel2(c01, a11, a00); a11 = sel2(c01, t, a11);
        t = v00; v00 = sel2(c01, v01, v00); v01 = sel2(c01, -t, v01);
        t = v10; v10 = sel2(c01, v11, v10); v11 = sel2(c01, -t, v11);
        t = v20; v20 = sel2(c01, v21, v20); v21 = sel2(c01, -t, v21);
    }
    {
        v2i c02 = a00 < a22;
        t = a00; a00 = sel2(c02, a22, a00); a22 = sel2(c02, t, a22);
        t = v00; v00 = sel2(c02, v02, v00); v02 = sel2(c02, -t, v02);
        t = v10; v10 = sel2(c02, v12, v10); v12 = sel2(c02, -t, v12);
        t = v20; v20 = sel2(c02, v22, v20); v22 = sel2(c02, -t, v22);
    }
    {
        v2i c12 = a11 < a22;
        t = a11; a11 = sel2(c12, a22, a11); a22 = sel2(c12, t, a22);
        t = v01; v01 = sel2(c12, v02, v01); v02 = sel2(c12, -t, v02);
        t = v11; v11 = sel2(c12, v12, v11); v12 = sel2(c12, -t, v12);
        t = v21; v21 = sel2(c12, v22, v21); v22 = sel2(c12, -t, v22);
    }

    v2f b00 = m00*v00 + m01*v10 + m02*v20;
    v2f b01 = m00*v01 + m01*v11 + m02*v21;
    v2f b02 = m00*v02 + m01*v12 + m02*v22;
    v2f b10 = m10*v00 + m11*v10 + m12*v20;
    v2f b11 = m10*v01 + m11*v11 + m12*v21;
    v2f b12 = m10*v02 + m11*v12 + m12*v22;
    v2f b20 = m20*v00 + m21*v10 + m22*v20;
    v2f b21 = m20*v01 + m21*v11 + m22*v21;
    v2f b22 = m20*v02 + m21*v12 + m22*v22;

    v2f u00 = (v2f)1.0f, u01 = (v2f)0.0f, u02 = (v2f)0.0f;
    v2f u10 = (v2f)0.0f, u11 = (v2f)1.0f, u12 = (v2f)0.0f;
    v2f u20 = (v2f)0.0f, u21 = (v2f)0.0f, u22 = (v2f)1.0f;

    givens2(b00, b10, b00, b01, b02, b10, b11, b12,
            u00, u10, u20, u01, u11, u21);
    givens2(b00, b20, b00, b01, b02, b20, b21, b22,
            u00, u10, u20, u02, u12, u22);
    givens2(b11, b21, b10, b11, b12, b20, b21, b22,
            u01, u11, u21, u02, u12, u22);

    r00 = u00*v00 + u01*v01 + u02*v02;
    r01 = u00*v10 + u01*v11 + u02*v12;
    r02 = u00*v20 + u01*v21 + u02*v22;
    r10 = u10*v00 + u11*v01 + u12*v02;
    r11 = u10*v10 + u11*v11 + u12*v12;
    r12 = u10*v20 + u11*v21 + u12*v22;
    r20 = u20*v00 + u21*v01 + u22*v02;
    r21 = u20*v10 + u21*v11 + u22*v12;
    r22 = u20*v20 + u21*v21 + u22*v22;
}

static __device__ __forceinline__ float4 ld_f4(const float* __restrict__ x, long f, long ntotf){
    if (f + 4 <= ntotf) return *(const float4*)(x + f);
    float4 r = make_float4(0.f, 0.f, 0.f, 0.f);
    if (f     < ntotf) r.x = x[f];
    if (f + 1 < ntotf) r.y = x[f + 1];
    if (f + 2 < ntotf) r.z = x[f + 2];
    if (f + 3 < ntotf) r.w = x[f + 3];
    return r;
}
static __device__ __forceinline__ void st_f4(float* __restrict__ o, long f, float4 v, long ntotf){
    if (f + 4 <= ntotf) { *(float4*)(o + f) = v; return; }
    if (f     < ntotf) o[f]     = v.x;
    if (f + 1 < ntotf) o[f + 1] = v.y;
    if (f + 2 < ntotf) o[f + 2] = v.z;
    if (f + 3 < ntotf) o[f + 3] = v.w;
}

// Wave-decoupled staging: each wave owns a private 4.6 KB LDS region and
// never synchronizes with other waves (NO __syncthreads anywhere). Lockstep
// wave execution + a wave-local s_waitcnt lgkmcnt(0) is a sufficient fence
// for the cross-lane LDS shuffle. Global access stays perfectly coalesced
// (float4, lane-consecutive); waves slide independently so HBM latency is
// hidden by TLP (18 KB/block -> 8 blocks/CU -> 32-wave cap).
__global__ __launch_bounds__(TPB) void svdo_kernel(const float* __restrict__ x,
                                                   float* __restrict__ out,
                                                   int nmat)
{
    __shared__ float lds[4][FPW];
    const int lane = threadIdx.x & 63;
    const int wv   = threadIdx.x >> 6;
    const long mbase = (long)blockIdx.x * MPB + (long)wv * MPW;
    const long fb    = mbase * 9;
    const long ntotf = (long)nmat * 9;
    float* L = lds[wv];

    // Stage in: 288 float4 per wave region, lane-consecutive (4.5/lane).
    #pragma unroll
    for (int k = 0; k < 5; ++k) {
        const int idx = lane + k * 64;
        if (idx < F4PW) {
            float4 v = ld_f4(x, fb + (long)idx * 4, ntotf);
            *(float4*)&L[idx * 4] = v;
        }
    }
    // Wave-local fence: all ds_writes (and their feeding global loads, via
    // register deps) complete before any cross-lane ds_read below.
    asm volatile("s_waitcnt lgkmcnt(0)" ::: "memory");
    __builtin_amdgcn_sched_barrier(0);

    // Each lane computes matrices (mbase+lane, mbase+lane+64).
    // Stride-9-float LDS reads: odd stride -> 2 lanes/bank (free).
    const float* p0 = &L[lane * 9];
    const float* p1 = &L[(lane + 64) * 9];
    v2f m00 = {p0[0], p1[0]}, m01 = {p0[1], p1[1]}, m02 = {p0[2], p1[2]};
    v2f m10 = {p0[3], p1[3]}, m11 = {p0[4], p1[4]}, m12 = {p0[5], p1[5]};
    v2f m20 = {p0[6], p1[6]}, m21 = {p0[7], p1[7]}, m22 = {p0[8], p1[8]};

    v2f r00, r01, r02, r10, r11, r12, r20, r21, r22;
    solve2(m00, m01, m02, m10, m11, m12, m20, m21, m22,
           r00, r01, r02, r10, r11, r12, r20, r21, r22);

    // Write results back to own region (same addresses just read -> no
    // cross-lane hazard within the compute phase).
    float* o0 = &L[lane * 9];
    o0[0]=r00.x; o0[1]=r01.x; o0[2]=r02.x;
    o0[3]=r10.x; o0[4]=r11.x; o0[5]=r12.x;
    o0[6]=r20.x; o0[7]=r21.x; o0[8]=r22.x;
    float* o1 = &L[(lane + 64) * 9];
    o1[0]=r00.y; o1[1]=r01.y; o1[2]=r02.y;
    o1[3]=r10.y; o1[4]=r11.y; o1[5]=r12.y;
    o1[6]=r20.y; o1[7]=r21.y; o1[8]=r22.y;

    // Wave-local fence before the cross-lane float4 readback.
    asm volatile("s_waitcnt lgkmcnt(0)" ::: "memory");
    __builtin_amdgcn_sched_barrier(0);

    // Stage out: coalesced float4 stores.
    #pragma unroll
    for (int k = 0; k < 5; ++k) {
        const int idx = lane + k * 64;
        if (idx < F4PW) {
            float4 v = *(const float4*)&L[idx * 4];
            st_f4(out, fb + (long)idx * 4, v, ntotf);
        }
    }
}

extern "C" void kernel_launch(void* const* d_in, const int* in_sizes, int n_in,
                              void* d_out, int out_size, void* d_ws, size_t ws_size,
                              hipStream_t stream)
{
    (void)n_in; (void)d_ws; (void)ws_size; (void)out_size;
    const float* x = (const float*)d_in[0];
    float* out = (float*)d_out;
    const int nmat = in_sizes[0] / 9;
    const int grid = (nmat + MPB - 1) / MPB;
    svdo_kernel<<<grid, TPB, 0, stream>>>(x, out, nmat);
}

// Round 7
// 35.722 us; speedup vs baseline: 1.2450x; 1.1188x over previous
//
#include <hip/hip_runtime.h>

#define TPB 256
#define MPW 128               // matrices per wave
#define FPW (MPW * 9)         // 1152 floats = 4608 B per wave region
#define F4PW (FPW / 4)        // 288 float4 per wave region
#define MPB (MPW * 4)         // 512 matrices per block (4 waves)

typedef float v2f __attribute__((ext_vector_type(2)));
typedef int   v2i __attribute__((ext_vector_type(2)));

static __device__ __forceinline__ v2f sqrt2(v2f a){
    v2f r; r.x = __builtin_amdgcn_sqrtf(a.x); r.y = __builtin_amdgcn_sqrtf(a.y); return r;
}
static __device__ __forceinline__ v2f rsq2(v2f a){
    v2f r; r.x = __builtin_amdgcn_rsqf(a.x); r.y = __builtin_amdgcn_rsqf(a.y); return r;
}
static __device__ __forceinline__ v2f csign2(v2f x, v2f y){
    v2f r; r.x = copysignf(x.x, y.x); r.y = copysignf(x.y, y.y); return r;
}
static __device__ __forceinline__ v2f fabs2(v2f x){
    v2f r; r.x = fabsf(x.x); r.y = fabsf(x.y); return r;
}
static __device__ __forceinline__ v2f sel2(v2i m, v2f a, v2f b){
    v2f r; r.x = m.x ? a.x : b.x; r.y = m.y ? a.y : b.y; return r;
}
static __device__ __forceinline__ void rot2(v2f &p, v2f &q, v2f c, v2f s){
    v2f x = p, y = q; p = c*x - s*y; q = s*x + c*y;
}

// Exact cyclic-Jacobi rotation (2 transcendentals), branchless. (unchanged)
static __device__ __forceinline__ void jrot2(v2f &app, v2f &aqq, v2f &apq,
                                             v2f &arp, v2f &arq,
                                             v2f &v0p, v2f &v1p, v2f &v2p,
                                             v2f &v0q, v2f &v1q, v2f &v2q)
{
    v2f d   = aqq - app;
    v2f w   = apq + apq;
    v2f nrm = d*d + w*w;
    v2f rr  = sqrt2(nrm);
    v2f sr  = csign2(rr, d);
    v2f den = d + sr;
    v2f inv = rsq2(den*den + w*w);
    v2f c   = fabs2(den) * inv;
    v2f s   = w * csign2(inv, den);
    v2i tiny = nrm < (v2f)1e-30f;
    c = sel2(tiny, (v2f)1.0f, c);
    s = sel2(tiny, (v2f)0.0f, s);
    v2f sum = app + aqq;
    v2f lo  = 0.5f*(sum - sr);
    app = lo; aqq = sum - lo; apq = (v2f)0.0f;
    rot2(arp, arq, c, s);
    rot2(v0p, v0q, c, s);
    rot2(v1p, v1q, c, s);
    rot2(v2p, v2q, c, s);
}

// SO(3) projection for 2 packed matrices.
// V from 3 cyclic Jacobi sweeps on M^T M (det(V)=+1 maintained through the
// sort by column negation). U built by Gram-Schmidt on b1,b2 (columns of
// B = M*V for the two LARGEST singular values) + cross product u3 = u1 x u2.
// R = u1 v1^T + u2 v2^T + u3 v3^T == U_ref diag(1,1,det(U_ref V_ref^T)) V_ref^T.
static __device__ __forceinline__ void solve2(
    v2f m00, v2f m01, v2f m02,
    v2f m10, v2f m11, v2f m12,
    v2f m20, v2f m21, v2f m22,
    v2f &r00, v2f &r01, v2f &r02,
    v2f &r10, v2f &r11, v2f &r12,
    v2f &r20, v2f &r21, v2f &r22)
{
    v2f a00 = m00*m00 + m10*m10 + m20*m20;
    v2f a11 = m01*m01 + m11*m11 + m21*m21;
    v2f a22 = m02*m02 + m12*m12 + m22*m22;
    v2f a01 = m00*m01 + m10*m11 + m20*m21;
    v2f a02 = m00*m02 + m10*m12 + m20*m22;
    v2f a12 = m01*m02 + m11*m12 + m21*m22;

    v2f v00 = (v2f)1.0f, v01 = (v2f)0.0f, v02 = (v2f)0.0f;
    v2f v10 = (v2f)0.0f, v11 = (v2f)1.0f, v12 = (v2f)0.0f;
    v2f v20 = (v2f)0.0f, v21 = (v2f)0.0f, v22 = (v2f)1.0f;

    #pragma unroll
    for (int sw = 0; sw < 3; ++sw) {
        jrot2(a00, a11, a01, a02, a12, v00, v10, v20, v01, v11, v21);
        jrot2(a00, a22, a02, a01, a12, v00, v10, v20, v02, v12, v22);
        jrot2(a11, a22, a12, a01, a02, v01, v11, v21, v02, v12, v22);
    }

    // Sort eigenvalues descending; column swap + negate keeps det(V)=+1.
    v2f t;
    {
        v2i c01 = a00 < a11;
        t = a00; a00 = sel2(c01, a11, a00); a11 = sel2(c01, t, a11);
        t = v00; v00 = sel2(c01, v01, v00); v01 = sel2(c01, -t, v01);
        t = v10; v10 = sel2(c01, v11, v10); v11 = sel2(c01, -t, v11);
        t = v20; v20 = sel2(c01, v21, v20); v21 = sel2(c01, -t, v21);
    }
    {
        v2i c02 = a00 < a22;
        t = a00; a00 = sel2(c02, a22, a00); a22 = sel2(c02, t, a22);
        t = v00; v00 = sel2(c02, v02, v00); v02 = sel2(c02, -t, v02);
        t = v10; v10 = sel2(c02, v12, v10); v12 = sel2(c02, -t, v12);
        t = v20; v20 = sel2(c02, v22, v20); v22 = sel2(c02, -t, v22);
    }
    {
        v2i c12 = a11 < a22;
        t = a11; a11 = sel2(c12, a22, a11); a22 = sel2(c12, t, a22);
        t = v01; v01 = sel2(c12, v02, v01); v02 = sel2(c12, -t, v02);
        t = v11; v11 = sel2(c12, v12, v11); v12 = sel2(c12, -t, v12);
        t = v21; v21 = sel2(c12, v22, v21); v22 = sel2(c12, -t, v22);
    }

    // b1, b2 = first two columns of M*V (third column never needed)
    v2f b00 = m00*v00 + m01*v10 + m02*v20;
    v2f b10 = m10*v00 + m11*v10 + m12*v20;
    v2f b20 = m20*v00 + m21*v10 + m22*v20;
    v2f b01 = m00*v01 + m01*v11 + m02*v21;
    v2f b11 = m10*v01 + m11*v11 + m12*v21;
    v2f b21 = m20*v01 + m21*v11 + m22*v21;

    // u1 = normalize(b1)
    v2f n1 = b00*b00 + b10*b10 + b20*b20;
    v2f i1 = rsq2(n1);
    v2i ok1 = n1 > (v2f)1e-30f;
    i1 = sel2(ok1, i1, (v2f)0.0f);
    v2f u00 = b00*i1, u10 = b10*i1, u20 = b20*i1;

    // u2 = normalize(b2 - (b2.u1) u1)
    v2f d12 = b01*u00 + b11*u10 + b21*u20;
    v2f q0 = b01 - d12*u00;
    v2f q1 = b11 - d12*u10;
    v2f q2 = b21 - d12*u20;
    v2f n2 = q0*q0 + q1*q1 + q2*q2;
    v2f i2 = rsq2(n2);
    v2i ok2 = n2 > (v2f)1e-30f;
    i2 = sel2(ok2, i2, (v2f)0.0f);
    v2f u01 = q0*i2, u11 = q1*i2, u21 = q2*i2;

    // u3 = u1 x u2 (det(U)=+1 by construction; carries the det(M) fix)
    v2f u02 = u10*u21 - u20*u11;
    v2f u12 = u20*u01 - u00*u21;
    v2f u22 = u00*u11 - u10*u01;

    // R = U * V^T
    r00 = u00*v00 + u01*v01 + u02*v02;
    r01 = u00*v10 + u01*v11 + u02*v12;
    r02 = u00*v20 + u01*v21 + u02*v22;
    r10 = u10*v00 + u11*v01 + u12*v02;
    r11 = u10*v10 + u11*v11 + u12*v12;
    r12 = u10*v20 + u11*v21 + u12*v22;
    r20 = u20*v00 + u21*v01 + u22*v02;
    r21 = u20*v10 + u21*v11 + u22*v12;
    r22 = u20*v20 + u21*v21 + u22*v22;
}

static __device__ __forceinline__ float4 ld_f4(const float* __restrict__ x, long f, long ntotf){
    if (f + 4 <= ntotf) return *(const float4*)(x + f);
    float4 r = make_float4(0.f, 0.f, 0.f, 0.f);
    if (f     < ntotf) r.x = x[f];
    if (f + 1 < ntotf) r.y = x[f + 1];
    if (f + 2 < ntotf) r.z = x[f + 2];
    if (f + 3 < ntotf) r.w = x[f + 3];
    return r;
}
static __device__ __forceinline__ void st_f4(float* __restrict__ o, long f, float4 v, long ntotf){
    if (f + 4 <= ntotf) { *(float4*)(o + f) = v; return; }
    if (f     < ntotf) o[f]     = v.x;
    if (f + 1 < ntotf) o[f + 1] = v.y;
    if (f + 2 < ntotf) o[f + 2] = v.z;
    if (f + 3 < ntotf) o[f + 3] = v.w;
}

// Wave-decoupled staging (round-6 structure, unchanged): each wave owns a
// private 4.6 KB LDS region; no __syncthreads anywhere; wave-local
// s_waitcnt lgkmcnt(0) fences the cross-lane LDS shuffles.
__global__ __launch_bounds__(TPB) void svdo_kernel(const float* __restrict__ x,
                                                   float* __restrict__ out,
                                                   int nmat)
{
    __shared__ float lds[4][FPW];
    const int lane = threadIdx.x & 63;
    const int wv   = threadIdx.x >> 6;
    const long mbase = (long)blockIdx.x * MPB + (long)wv * MPW;
    const long fb    = mbase * 9;
    const long ntotf = (long)nmat * 9;
    float* L = lds[wv];

    #pragma unroll
    for (int k = 0; k < 5; ++k) {
        const int idx = lane + k * 64;
        if (idx < F4PW) {
            float4 v = ld_f4(x, fb + (long)idx * 4, ntotf);
            *(float4*)&L[idx * 4] = v;
        }
    }
    asm volatile("s_waitcnt lgkmcnt(0)" ::: "memory");
    __builtin_amdgcn_sched_barrier(0);

    const float* p0 = &L[lane * 9];
    const float* p1 = &L[(lane + 64) * 9];
    v2f m00 = {p0[0], p1[0]}, m01 = {p0[1], p1[1]}, m02 = {p0[2], p1[2]};
    v2f m10 = {p0[3], p1[3]}, m11 = {p0[4], p1[4]}, m12 = {p0[5], p1[5]};
    v2f m20 = {p0[6], p1[6]}, m21 = {p0[7], p1[7]}, m22 = {p0[8], p1[8]};

    v2f r00, r01, r02, r10, r11, r12, r20, r21, r22;
    solve2(m00, m01, m02, m10, m11, m12, m20, m21, m22,
           r00, r01, r02, r10, r11, r12, r20, r21, r22);

    float* o0 = &L[lane * 9];
    o0[0]=r00.x; o0[1]=r01.x; o0[2]=r02.x;
    o0[3]=r10.x; o0[4]=r11.x; o0[5]=r12.x;
    o0[6]=r20.x; o0[7]=r21.x; o0[8]=r22.x;
    float* o1 = &L[(lane + 64) * 9];
    o1[0]=r00.y; o1[1]=r01.y; o1[2]=r02.y;
    o1[3]=r10.y; o1[4]=r11.y; o1[5]=r12.y;
    o1[6]=r20.y; o1[7]=r21.y; o1[8]=r22.y;

    asm volatile("s_waitcnt lgkmcnt(0)" ::: "memory");
    __builtin_amdgcn_sched_barrier(0);

    #pragma unroll
    for (int k = 0; k < 5; ++k) {
        const int idx = lane + k * 64;
        if (idx < F4PW) {
            float4 v = *(const float4*)&L[idx * 4];
            st_f4(out, fb + (long)idx * 4, v, ntotf);
        }
    }
}

extern "C" void kernel_launch(void* const* d_in, const int* in_sizes, int n_in,
                              void* d_out, int out_size, void* d_ws, size_t ws_size,
                              hipStream_t stream)
{
    (void)n_in; (void)d_ws; (void)ws_size; (void)out_size;
    const float* x = (const float*)d_in[0];
    float* out = (float*)d_out;
    const int nmat = in_sizes[0] / 9;
    const int grid = (nmat + MPB - 1) / MPB;
    svdo_kernel<<<grid, TPB, 0, stream>>>(x, out, nmat);
}

// Round 8
// 33.482 us; speedup vs baseline: 1.3283x; 1.0669x over previous
//
#include <hip/hip_runtime.h>

#define TPB 256
#define MPW 128               // matrices per tile (per wave)
#define FPW (MPW * 9)         // 1152 floats = 4608 B per tile buffer
#define F4PW (FPW / 4)        // 288 float4 per tile

typedef float v2f __attribute__((ext_vector_type(2)));
typedef int   v2i __attribute__((ext_vector_type(2)));

static __device__ __forceinline__ v2f sqrt2(v2f a){
    v2f r; r.x = __builtin_amdgcn_sqrtf(a.x); r.y = __builtin_amdgcn_sqrtf(a.y); return r;
}
static __device__ __forceinline__ v2f rsq2(v2f a){
    v2f r; r.x = __builtin_amdgcn_rsqf(a.x); r.y = __builtin_amdgcn_rsqf(a.y); return r;
}
static __device__ __forceinline__ v2f csign2(v2f x, v2f y){
    v2f r; r.x = copysignf(x.x, y.x); r.y = copysignf(x.y, y.y); return r;
}
static __device__ __forceinline__ v2f fabs2(v2f x){
    v2f r; r.x = fabsf(x.x); r.y = fabsf(x.y); return r;
}
static __device__ __forceinline__ v2f sel2(v2i m, v2f a, v2f b){
    v2f r; r.x = m.x ? a.x : b.x; r.y = m.y ? a.y : b.y; return r;
}
static __device__ __forceinline__ void rot2(v2f &p, v2f &q, v2f c, v2f s){
    v2f x = p, y = q; p = c*x - s*y; q = s*x + c*y;
}

// Exact cyclic-Jacobi rotation (2 transcendentals), branchless. (unchanged)
static __device__ __forceinline__ void jrot2(v2f &app, v2f &aqq, v2f &apq,
                                             v2f &arp, v2f &arq,
                                             v2f &v0p, v2f &v1p, v2f &v2p,
                                             v2f &v0q, v2f &v1q, v2f &v2q)
{
    v2f d   = aqq - app;
    v2f w   = apq + apq;
    v2f nrm = d*d + w*w;
    v2f rr  = sqrt2(nrm);
    v2f sr  = csign2(rr, d);
    v2f den = d + sr;
    v2f inv = rsq2(den*den + w*w);
    v2f c   = fabs2(den) * inv;
    v2f s   = w * csign2(inv, den);
    v2i tiny = nrm < (v2f)1e-30f;
    c = sel2(tiny, (v2f)1.0f, c);
    s = sel2(tiny, (v2f)0.0f, s);
    v2f sum = app + aqq;
    v2f lo  = 0.5f*(sum - sr);
    app = lo; aqq = sum - lo; apq = (v2f)0.0f;
    rot2(arp, arq, c, s);
    rot2(v0p, v0q, c, s);
    rot2(v1p, v1q, c, s);
    rot2(v2p, v2q, c, s);
}

// SO(3) projection for 2 packed matrices (round-7 version, verified):
// V from 3 Jacobi sweeps; U via Gram-Schmidt on b1,b2 + u3 = u1 x u2.
static __device__ __forceinline__ void solve2(
    v2f m00, v2f m01, v2f m02,
    v2f m10, v2f m11, v2f m12,
    v2f m20, v2f m21, v2f m22,
    v2f &r00, v2f &r01, v2f &r02,
    v2f &r10, v2f &r11, v2f &r12,
    v2f &r20, v2f &r21, v2f &r22)
{
    v2f a00 = m00*m00 + m10*m10 + m20*m20;
    v2f a11 = m01*m01 + m11*m11 + m21*m21;
    v2f a22 = m02*m02 + m12*m12 + m22*m22;
    v2f a01 = m00*m01 + m10*m11 + m20*m21;
    v2f a02 = m00*m02 + m10*m12 + m20*m22;
    v2f a12 = m01*m02 + m11*m12 + m21*m22;

    v2f v00 = (v2f)1.0f, v01 = (v2f)0.0f, v02 = (v2f)0.0f;
    v2f v10 = (v2f)0.0f, v11 = (v2f)1.0f, v12 = (v2f)0.0f;
    v2f v20 = (v2f)0.0f, v21 = (v2f)0.0f, v22 = (v2f)1.0f;

    #pragma unroll
    for (int sw = 0; sw < 3; ++sw) {
        jrot2(a00, a11, a01, a02, a12, v00, v10, v20, v01, v11, v21);
        jrot2(a00, a22, a02, a01, a12, v00, v10, v20, v02, v12, v22);
        jrot2(a11, a22, a12, a01, a02, v01, v11, v21, v02, v12, v22);
    }

    v2f t;
    {
        v2i c01 = a00 < a11;
        t = a00; a00 = sel2(c01, a11, a00); a11 = sel2(c01, t, a11);
        t = v00; v00 = sel2(c01, v01, v00); v01 = sel2(c01, -t, v01);
        t = v10; v10 = sel2(c01, v11, v10); v11 = sel2(c01, -t, v11);
        t = v20; v20 = sel2(c01, v21, v20); v21 = sel2(c01, -t, v21);
    }
    {
        v2i c02 = a00 < a22;
        t = a00; a00 = sel2(c02, a22, a00); a22 = sel2(c02, t, a22);
        t = v00; v00 = sel2(c02, v02, v00); v02 = sel2(c02, -t, v02);
        t = v10; v10 = sel2(c02, v12, v10); v12 = sel2(c02, -t, v12);
        t = v20; v20 = sel2(c02, v22, v20); v22 = sel2(c02, -t, v22);
    }
    {
        v2i c12 = a11 < a22;
        t = a11; a11 = sel2(c12, a22, a11); a22 = sel2(c12, t, a22);
        t = v01; v01 = sel2(c12, v02, v01); v02 = sel2(c12, -t, v02);
        t = v11; v11 = sel2(c12, v12, v11); v12 = sel2(c12, -t, v12);
        t = v21; v21 = sel2(c12, v22, v21); v22 = sel2(c12, -t, v22);
    }

    v2f b00 = m00*v00 + m01*v10 + m02*v20;
    v2f b10 = m10*v00 + m11*v10 + m12*v20;
    v2f b20 = m20*v00 + m21*v10 + m22*v20;
    v2f b01 = m00*v01 + m01*v11 + m02*v21;
    v2f b11 = m10*v01 + m11*v11 + m12*v21;
    v2f b21 = m20*v01 + m21*v11 + m22*v21;

    v2f n1 = b00*b00 + b10*b10 + b20*b20;
    v2f i1 = rsq2(n1);
    v2i ok1 = n1 > (v2f)1e-30f;
    i1 = sel2(ok1, i1, (v2f)0.0f);
    v2f u00 = b00*i1, u10 = b10*i1, u20 = b20*i1;

    v2f d12 = b01*u00 + b11*u10 + b21*u20;
    v2f q0 = b01 - d12*u00;
    v2f q1 = b11 - d12*u10;
    v2f q2 = b21 - d12*u20;
    v2f n2 = q0*q0 + q1*q1 + q2*q2;
    v2f i2 = rsq2(n2);
    v2i ok2 = n2 > (v2f)1e-30f;
    i2 = sel2(ok2, i2, (v2f)0.0f);
    v2f u01 = q0*i2, u11 = q1*i2, u21 = q2*i2;

    v2f u02 = u10*u21 - u20*u11;
    v2f u12 = u20*u01 - u00*u21;
    v2f u22 = u00*u11 - u10*u01;

    r00 = u00*v00 + u01*v01 + u02*v02;
    r01 = u00*v10 + u01*v11 + u02*v12;
    r02 = u00*v20 + u01*v21 + u02*v22;
    r10 = u10*v00 + u11*v01 + u12*v02;
    r11 = u10*v10 + u11*v11 + u12*v12;
    r12 = u10*v20 + u11*v21 + u12*v22;
    r20 = u20*v00 + u21*v01 + u22*v02;
    r21 = u20*v10 + u21*v11 + u22*v12;
    r22 = u20*v20 + u21*v21 + u22*v22;
}

static __device__ __forceinline__ float4 ld_f4(const float* __restrict__ x, long f, long ntotf){
    if (f + 4 <= ntotf) return *(const float4*)(x + f);
    float4 r = make_float4(0.f, 0.f, 0.f, 0.f);
    if (f     < ntotf) r.x = x[f];
    if (f + 1 < ntotf) r.y = x[f + 1];
    if (f + 2 < ntotf) r.z = x[f + 2];
    if (f + 3 < ntotf) r.w = x[f + 3];
    return r;
}
static __device__ __forceinline__ void st_f4(float* __restrict__ o, long f, float4 v, long ntotf){
    if (f + 4 <= ntotf) { *(float4*)(o + f) = v; return; }
    if (f     < ntotf) o[f]     = v.x;
    if (f + 1 < ntotf) o[f + 1] = v.y;
    if (f + 2 < ntotf) o[f + 2] = v.z;
    if (f + 3 < ntotf) o[f + 3] = v.w;
}

// Wave-local double-buffered persistent pipeline. Each wave owns TWO private
// 4.6 KB LDS buffers and grid-strides over 128-matrix tiles. NO __syncthreads
// anywhere (this is what lets global loads stay in flight across phases —
// there is no barrier for the compiler to drain vmcnt at). Per iteration:
//   land prefetched regs -> buf[cur]; lgkmcnt(0);
//   ISSUE next tile's global loads (in flight under compute);
//   compute from buf[cur]; write back; lgkmcnt(0); coalesced stores.
// LLVM's waitcnt pass emits a COUNTED vmcnt before the landing ds_writes
// (loads are older than the previous iteration's stores), so stores never
// stall the loop.
__global__ __launch_bounds__(TPB) void svdo_kernel(const float* __restrict__ x,
                                                   float* __restrict__ out,
                                                   int nmat, int ntiles, int W)
{
    __shared__ float lds[4][2 * FPW];   // 36864 B -> 4 blocks/CU -> 16 waves/CU
    const int lane = threadIdx.x & 63;
    const int wv   = threadIdx.x >> 6;
    const long ntotf = (long)nmat * 9;

    int tile = blockIdx.x * 4 + wv;
    if (tile >= ntiles) return;

    float* bufA = &lds[wv][0];
    float* bufB = &lds[wv][FPW];

    float4 q0, q1, q2, q3, q4;
    {   // prologue: issue loads for first tile
        const long fb = (long)tile * FPW;
        q0 = ld_f4(x, fb + (long)(lane       ) * 4, ntotf);
        q1 = ld_f4(x, fb + (long)(lane +  64) * 4, ntotf);
        q2 = ld_f4(x, fb + (long)(lane + 128) * 4, ntotf);
        q3 = ld_f4(x, fb + (long)(lane + 192) * 4, ntotf);
        q4 = make_float4(0.f, 0.f, 0.f, 0.f);
        if (lane < 32) q4 = ld_f4(x, fb + (long)(lane + 256) * 4, ntotf);
    }

    for (;;) {
        // Land prefetched tile into bufA (counted vmcnt wait, stores excluded).
        *(float4*)&bufA[(lane       ) * 4] = q0;
        *(float4*)&bufA[(lane +  64) * 4] = q1;
        *(float4*)&bufA[(lane + 128) * 4] = q2;
        *(float4*)&bufA[(lane + 192) * 4] = q3;
        if (lane < 32) *(float4*)&bufA[(lane + 256) * 4] = q4;
        // Wave-local fence: ds_writes complete (cross-lane visible, q consumed)
        asm volatile("s_waitcnt lgkmcnt(0)" ::: "memory");

        const int  nxt  = tile + W;
        const bool have = nxt < ntiles;
        if (have) {   // issue next tile's loads — in flight under compute
            const long fb = (long)nxt * FPW;
            q0 = ld_f4(x, fb + (long)(lane       ) * 4, ntotf);
            q1 = ld_f4(x, fb + (long)(lane +  64) * 4, ntotf);
            q2 = ld_f4(x, fb + (long)(lane + 128) * 4, ntotf);
            q3 = ld_f4(x, fb + (long)(lane + 192) * 4, ntotf);
            if (lane < 32) q4 = ld_f4(x, fb + (long)(lane + 256) * 4, ntotf);
        }

        // Compute 2 matrices from bufA (stride-9 reads: 2/bank, free).
        {
            const float* p0 = &bufA[lane * 9];
            const float* p1 = &bufA[(lane + 64) * 9];
            v2f m00 = {p0[0], p1[0]}, m01 = {p0[1], p1[1]}, m02 = {p0[2], p1[2]};
            v2f m10 = {p0[3], p1[3]}, m11 = {p0[4], p1[4]}, m12 = {p0[5], p1[5]};
            v2f m20 = {p0[6], p1[6]}, m21 = {p0[7], p1[7]}, m22 = {p0[8], p1[8]};

            v2f r00, r01, r02, r10, r11, r12, r20, r21, r22;
            solve2(m00, m01, m02, m10, m11, m12, m20, m21, m22,
                   r00, r01, r02, r10, r11, r12, r20, r21, r22);

            float* o0 = &bufA[lane * 9];
            o0[0]=r00.x; o0[1]=r01.x; o0[2]=r02.x;
            o0[3]=r10.x; o0[4]=r11.x; o0[5]=r12.x;
            o0[6]=r20.x; o0[7]=r21.x; o0[8]=r22.x;
            float* o1 = &bufA[(lane + 64) * 9];
            o1[0]=r00.y; o1[1]=r01.y; o1[2]=r02.y;
            o1[3]=r10.y; o1[4]=r11.y; o1[5]=r12.y;
            o1[6]=r20.y; o1[7]=r21.y; o1[8]=r22.y;
        }
        // Wave-local fence before cross-lane float4 readback.
        asm volatile("s_waitcnt lgkmcnt(0)" ::: "memory");

        // Coalesced stores (fire-and-forget; never waited on in-loop).
        {
            const long fb = (long)tile * FPW;
            st_f4(out, fb + (long)(lane       ) * 4, *(const float4*)&bufA[(lane       ) * 4], ntotf);
            st_f4(out, fb + (long)(lane +  64) * 4, *(const float4*)&bufA[(lane +  64) * 4], ntotf);
            st_f4(out, fb + (long)(lane + 128) * 4, *(const float4*)&bufA[(lane + 128) * 4], ntotf);
            st_f4(out, fb + (long)(lane + 192) * 4, *(const float4*)&bufA[(lane + 192) * 4], ntotf);
            if (lane < 32)
                st_f4(out, fb + (long)(lane + 256) * 4, *(const float4*)&bufA[(lane + 256) * 4], ntotf);
        }

        if (!have) break;
        tile = nxt;
        float* ts = bufA; bufA = bufB; bufB = ts;   // ping-pong buffers
    }
}

extern "C" void kernel_launch(void* const* d_in, const int* in_sizes, int n_in,
                              void* d_out, int out_size, void* d_ws, size_t ws_size,
                              hipStream_t stream)
{
    (void)n_in; (void)d_ws; (void)ws_size; (void)out_size;
    const float* x = (const float*)d_in[0];
    float* out = (float*)d_out;
    const int nmat = in_sizes[0] / 9;
    const int ntiles = (nmat + MPW - 1) / MPW;
    int grid = (ntiles + 3) / 4;          // blocks if one tile per wave
    if (grid > 1024) grid = 1024;         // persistent: ~3.8 tiles/wave at 2M
    const int W = grid * 4;               // total waves = tile stride
    svdo_kernel<<<grid, TPB, 0, stream>>>(x, out, nmat, ntiles, W);
}